// Round 8
// baseline (6511.116 us; speedup 1.0000x reference)
//
#include <hip/hip_runtime.h>
#include <stdint.h>

// AutoRegressiveLSTM: B=128, T=1024, I=128, H=1024, O=128. 4H=4096, K=I+H (+O fused)
#define Tn 1024
#define In 128

typedef __attribute__((ext_vector_type(8))) short short8;
typedef __attribute__((ext_vector_type(4))) float f32x4;
typedef unsigned long long u64;

// ---- workspace layout (bytes) ----
#define WS_WFRAG  0ull                         // 256ut*40kt*64lane*16B = 10,485,760
#define WS_WOUT   (WS_WFRAG + 10485760ull)     // 8u*32kt*1024B = 262,144
#define WS_Z0     (WS_WOUT + 262144ull)        // 8m*4kt*1024B = 32,768
#define WS_HBUF   (WS_Z0 + 32768ull)           // 2buf*8m*32kt*1024B = 524,288
#define WS_BIAS   (WS_HBUF + 524288ull)        // 4096*4
#define WS_CNT    (WS_BIAS + 16384ull)         // 8m*1024t*4B flags (line-disjoint per group)
// total ~11.35 MB

__device__ __forceinline__ unsigned short f2bf(float f) {
  unsigned u = __builtin_bit_cast(unsigned, f);
  return (unsigned short)((u + 0x7FFFu + ((u >> 16) & 1u)) >> 16);  // RNE
}
__device__ __forceinline__ float fast_sig(float v) {
  float e = __builtin_amdgcn_exp2f(-1.44269504089f * v);
  return __builtin_amdgcn_rcpf(1.0f + e);
}
__device__ __forceinline__ float fast_tanh(float v) {
  float a = fabsf(v);
  float e = __builtin_amdgcn_exp2f(-2.88539008178f * a);
  float r = (1.0f - e) * __builtin_amdgcn_rcpf(1.0f + e);
  return copysignf(r, v);
}

// ---------------------------------------------------------------------------
// K1: fused weights -> bf16 fragments (MFMA A operand). Layout (R6-proven):
// wfrag[ut][kt][lane][8], ut = global row-tile 0..255 covering units ut*4..+4;
// within tile, row r: unit = ut*4 + (r>>2), gate = r&3 ->
//   n = (col&3)*1024 + ut*4 + (col>>2), col = lane&15.
// ---------------------------------------------------------------------------
__global__ void k_wfrag(const float* __restrict__ Wih, const float* __restrict__ Whh,
                        const float* __restrict__ Wout, char* __restrict__ ws) {
  const int u = blockIdx.x, nt = blockIdx.y, kt = blockIdx.z;
  const int lane = threadIdx.x;
  const int col = lane & 15, quad = lane >> 4;
  const int n = (col & 3) * 1024 + u * 32 + nt * 4 + (col >> 2);
  float v[8];
  if (kt < 32) {
    const int k = kt * 32 + quad * 8;
    #pragma unroll
    for (int e = 0; e < 8; e++) v[e] = Whh[(size_t)n * 1024 + k + e];
    const float* wo = Wih + (size_t)n * 256 + 128;
    for (int o = 0; o < 128; o++) {
      const float wv = wo[o];
      const float* wr = Wout + (size_t)o * 1024 + k;
      #pragma unroll
      for (int e = 0; e < 8; e++) v[e] = fmaf(wv, wr[e], v[e]);
    }
  } else if (kt < 36) {
    const int k = (kt - 32) * 32 + quad * 8;
    #pragma unroll
    for (int e = 0; e < 8; e++) v[e] = Wih[(size_t)n * 256 + k + e];
  } else {
    const int o = (kt - 36) * 32 + quad * 8;
    #pragma unroll
    for (int e = 0; e < 8; e++) v[e] = Wih[(size_t)n * 256 + 128 + o + e];
  }
  short8 pk;
  #pragma unroll
  for (int e = 0; e < 8; e++) pk[e] = (short)f2bf(v[e]);
  *(short8*)(ws + WS_WFRAG + ((size_t)((u * 8 + nt) * 40 + kt) * 64 + lane) * 16) = pk;
}

// ---------------------------------------------------------------------------
// K2: misc setup (woutfrag, hn->frag into hbuf[1], z0 frag, bias2, flag zero)
// ---------------------------------------------------------------------------
__global__ void k_misc(const float* __restrict__ Wout, const float* __restrict__ hn,
                       const float* __restrict__ out_t, const float* __restrict__ bout,
                       const float* __restrict__ bih, const float* __restrict__ bhh,
                       const float* __restrict__ Wih, float* __restrict__ outp,
                       char* __restrict__ ws) {
  const int blk = blockIdx.x, lane = threadIdx.x;
  const int col = lane & 15, quad = lane >> 4;
  if (blk < 256) {                       // woutfrag[u][kt][lane][8] = Wout[o][j]
    const int u = blk >> 5, kt = blk & 31;
    const int o = u * 16 + col, j0 = kt * 32 + quad * 8;
    short8 pk;
    #pragma unroll
    for (int e = 0; e < 8; e++) pk[e] = (short)f2bf(Wout[(size_t)o * 1024 + j0 + e]);
    *(short8*)(ws + WS_WOUT + ((size_t)(u * 32 + kt) * 64 + lane) * 16) = pk;
  } else if (blk < 512) {                // hn -> frag layout into hbuf[1] (col=batch)
    const int t2 = blk - 256;
    const int mm = t2 >> 5, kt = t2 & 31;
    const int b = mm * 16 + col, j0 = kt * 32 + quad * 8;
    short8 pk;
    #pragma unroll
    for (int e = 0; e < 8; e++) pk[e] = (short)f2bf(hn[(size_t)b * 1024 + j0 + e]);
    *(short8*)(ws + WS_HBUF + ((size_t)((8 + mm) * 32 + kt) * 64 + lane) * 16) = pk;
  } else if (blk < 544) {                // z0 = output_t - b_out - hn@Wout^T (frag bf16)
    const int t2 = blk - 512;
    const int mm = t2 >> 2, kz = t2 & 3;
    const int b = mm * 16 + col;
    const int o0 = kz * 32 + quad * 8;
    float acc[8];
    #pragma unroll
    for (int e = 0; e < 8; e++) acc[e] = out_t[(size_t)b * 128 + o0 + e] - bout[o0 + e];
    for (int j = 0; j < 1024; j += 4) {
      const f32x4 h4 = *(const f32x4*)(hn + (size_t)b * 1024 + j);
      #pragma unroll
      for (int e = 0; e < 8; e++) {
        const f32x4 w4 = *(const f32x4*)(Wout + (size_t)(o0 + e) * 1024 + j);
        acc[e] -= h4[0] * w4[0] + h4[1] * w4[1] + h4[2] * w4[2] + h4[3] * w4[3];
      }
    }
    short8 pk;
    #pragma unroll
    for (int e = 0; e < 8; e++) pk[e] = (short)f2bf(acc[e]);
    *(short8*)(ws + WS_Z0 + ((size_t)(mm * 4 + kz) * 64 + lane) * 16) = pk;
  } else if (blk < 608) {                // bias2[n] = b_ih + b_hh + W_ihO @ b_out
    const int n = (blk - 544) * 64 + lane;
    float v = bih[n] + bhh[n];
    const float* wo = Wih + (size_t)n * 256 + 128;
    for (int o = 0; o < 128; o++) v = fmaf(wo[o], bout[o], v);
    ((float*)(ws + WS_BIAS))[n] = v;
  } else {                               // zero flag counters (8192 ints)
    int* c = (int*)(ws + WS_CNT);
    const int base = ((blk - 608) * 64 + lane) * 16;
    #pragma unroll
    for (int k = 0; k < 16; k++) c[base + k] = 0;
  }
  (void)outp;
}

// ---------------------------------------------------------------------------
// Main persistent kernel, round-8: TWO-GROUP SOFTWARE PIPELINE.
// Grid 256 WGs x 512 thr. WG (p = wg>>6, v = wg&63) serves pair of batch
// groups A = 2p, B = 2p+1 (16 batches each), units [v*16, v*16+16).
// Waves: grp = w>>2 (0 -> A, 1 -> B), wt = w&3 (row-tile of 4 units).
// Weights are group-independent: wave w holds bfr for tile ut = v*4+wt and
// uses it for its group. Per iteration (= one t for BOTH groups):
//   P0 stage xA(+z0A) | spinA(t-1)        } A's flag/h latency hidden under
//   P1 stage hA(t-1)                      } B's phases of the PREVIOUS iter
//   P2 gatesA(waves0-3) || ysA(t-1)(v<8, waves4-7)
//   P3 publishA (wave0, MALL) | ysA reduce(tid256+) | z0B(t=0) | spinB(tid64)
//   P4 stage hB(t-1) + xB(t)              } B's latency hidden under A's
//   P5 gatesB(waves4-7) || ysB(t-1)(v in 8..16, waves0-3)
//   P6 publishB (wave4) | ysB reduce(tid<256)
// Sync protocol: byte-identical to the R0/R2-proven system-scope (MALL) one
// (relaxed SYSTEM data ld/st; producer s_waitcnt vmcnt(0) before fetch_add;
// consumer relaxed spin; cnt[g*1024+t] line-disjoint, counts to 64).
// No XCD detection / sc0 paths (pairs span XCDs; latency is hidden, not
// avoided). LDS ~46 KB; one h buffer reused A->B within the iteration.
// ---------------------------------------------------------------------------
__launch_bounds__(512, 2)
__global__ void k_main(const float* __restrict__ x, const int* __restrict__ seq,
                       const float* __restrict__ cn, const float* __restrict__ b_out,
                       float* __restrict__ out, char* __restrict__ ws) {
  __shared__ short8 a_lds[40 * 64];        // 32 h + 4 x + 4 z0 kts (40 KB), reused A/B
  __shared__ u64    htile[64];             // 512B publish tile, reused A/B
  __shared__ float  ysred[4 * 16 * 20];    // ys partials [q][o][b] (5 KB)
  __shared__ float  bo_lds[16];
  __shared__ int    seq_lds[32];

  const int tid  = threadIdx.x;
  const int lane = tid & 63;
  const int w    = tid >> 6;
  const int wg   = blockIdx.x;
  const int p    = wg >> 6;                // pair 0..3
  const int v    = wg & 63;                // unit-slot 0..63
  const int grp  = w >> 2;                 // 0 = group A, 1 = group B
  const int wt   = w & 3;                  // row-tile within the WG's 16 units
  const int col16 = lane & 15, quad = lane >> 4;
  const int ut   = v * 4 + wt;             // global row-tile 0..255
  const int junit = ut * 4 + quad;         // this thread's unit 0..1023
  const int gA = p * 2, gB = p * 2 + 1;

  int* cnt = (int*)(ws + WS_CNT);
  const char* wfrag = ws + WS_WFRAG;
  const char* woutf = ws + WS_WOUT;
  char* hbuf = ws + WS_HBUF;
  const float* bias2 = (const float*)(ws + WS_BIAS);

  // persistent weight fragments: 40 x 16B = 160 VGPRs (waves w and w+4 alias)
  short8 bfr[40];
  {
    const char* base = wfrag + ((size_t)ut * 40 * 64) * 16 + (size_t)lane * 16;
    #pragma unroll
    for (int kt = 0; kt < 40; kt++) bfr[kt] = *(const short8*)(base + (size_t)kt * 1024);
  }
  if (tid < 32) seq_lds[tid] = seq[p * 32 + tid];
  if (tid < 16 && v < 16) bo_lds[tid] = b_out[(v & 7) * 16 + tid];
  float bias_g[4];
  #pragma unroll
  for (int j = 0; j < 4; j++) bias_g[j] = bias2[j * 1024 + junit];
  // c state: wave's group, batch col16, unit junit
  float c_reg = cn[(size_t)(p * 32 + grp * 16 + col16) * 1024 + junit];
  __syncthreads();

  #pragma unroll 1
  for (int tt = 0; tt <= Tn; tt++) {
    // ================ P0: stage xA(t) + z0A(t=0); spin A(t-1) ================
    if (tt < Tn && tid < 256) {
      const int kt4 = tid >> 6, ln = tid & 63;
      const int b = ln & 15, qd = ln >> 4;
      const int i0 = kt4 * 32 + qd * 8;
      const float* xp = x + ((size_t)(p * 32 + b) * Tn + tt) * In + i0;
      const float mk = (tt < seq_lds[b]) ? 1.0f : 0.0f;
      const f32x4 x0 = *(const f32x4*)xp;
      const f32x4 x1 = *(const f32x4*)(xp + 4);
      short8 pk;
      pk[0] = (short)f2bf(x0[0] * mk); pk[1] = (short)f2bf(x0[1] * mk);
      pk[2] = (short)f2bf(x0[2] * mk); pk[3] = (short)f2bf(x0[3] * mk);
      pk[4] = (short)f2bf(x1[0] * mk); pk[5] = (short)f2bf(x1[1] * mk);
      pk[6] = (short)f2bf(x1[2] * mk); pk[7] = (short)f2bf(x1[3] * mk);
      a_lds[(32 + kt4) * 64 + ln] = pk;
    }
    if (tt == 0 && tid >= 256) {
      const int kz = (tid - 256) >> 6, ln = tid & 63;
      a_lds[(36 + kz) * 64 + ln] =
          *(const short8*)(ws + WS_Z0 + ((size_t)(gA * 4 + kz) * 64 + ln) * 16);
    }
    if (tt >= 1 && tid == 0) {
      while (__hip_atomic_load(&cnt[gA * 1024 + (tt - 1)], __ATOMIC_RELAXED,
                               __HIP_MEMORY_SCOPE_SYSTEM) < 64) {}
    }
    __syncthreads();  // s1
    // ================ P1: stage hA(t-1) (32 KB, MALL) ================
    {
      const u64* src = (const u64*)(hbuf + (size_t)((((tt + 1) & 1) * 8) + gA) * 32768);
      u64 tmp[8];
      #pragma unroll
      for (int s = 0; s < 8; s++)
        tmp[s] = __hip_atomic_load(&src[s * 512 + tid], __ATOMIC_RELAXED,
                                   __HIP_MEMORY_SCOPE_SYSTEM);
      u64* dst = (u64*)a_lds;
      #pragma unroll
      for (int s = 0; s < 8; s++) dst[s * 512 + tid] = tmp[s];
    }
    __syncthreads();  // s2
    // ================ P2: gates A (waves 0-3) || ysA(t-1) (v<8, waves 4-7) ===
    if (tt < Tn && grp == 0) {
      f32x4 acc0 = {bias_g[0], bias_g[1], bias_g[2], bias_g[3]};
      f32x4 acc1 = {0.f, 0.f, 0.f, 0.f};
      f32x4 acc2 = {0.f, 0.f, 0.f, 0.f};
      f32x4 acc3 = {0.f, 0.f, 0.f, 0.f};
      #pragma unroll
      for (int kk = 0; kk < 9; kk++) {
        const short8 a0 = a_lds[(kk * 4 + 0) * 64 + lane];
        const short8 a1 = a_lds[(kk * 4 + 1) * 64 + lane];
        const short8 a2 = a_lds[(kk * 4 + 2) * 64 + lane];
        const short8 a3 = a_lds[(kk * 4 + 3) * 64 + lane];
        acc0 = __builtin_amdgcn_mfma_f32_16x16x32_bf16(bfr[kk * 4 + 0], a0, acc0, 0, 0, 0);
        acc1 = __builtin_amdgcn_mfma_f32_16x16x32_bf16(bfr[kk * 4 + 1], a1, acc1, 0, 0, 0);
        acc2 = __builtin_amdgcn_mfma_f32_16x16x32_bf16(bfr[kk * 4 + 2], a2, acc2, 0, 0, 0);
        acc3 = __builtin_amdgcn_mfma_f32_16x16x32_bf16(bfr[kk * 4 + 3], a3, acc3, 0, 0, 0);
      }
      if (tt == 0) {
        const short8 z0 = a_lds[36 * 64 + lane];
        const short8 z1 = a_lds[37 * 64 + lane];
        const short8 z2 = a_lds[38 * 64 + lane];
        const short8 z3 = a_lds[39 * 64 + lane];
        acc0 = __builtin_amdgcn_mfma_f32_16x16x32_bf16(bfr[36], z0, acc0, 0, 0, 0);
        acc1 = __builtin_amdgcn_mfma_f32_16x16x32_bf16(bfr[37], z1, acc1, 0, 0, 0);
        acc2 = __builtin_amdgcn_mfma_f32_16x16x32_bf16(bfr[38], z2, acc2, 0, 0, 0);
        acc3 = __builtin_amdgcn_mfma_f32_16x16x32_bf16(bfr[39], z3, acc3, 0, 0, 0);
      }
      const float Gi = acc0[0] + acc1[0] + acc2[0] + acc3[0];
      const float Gf = acc0[1] + acc1[1] + acc2[1] + acc3[1];
      const float Gg = acc0[2] + acc1[2] + acc2[2] + acc3[2];
      const float Go = acc0[3] + acc1[3] + acc2[3] + acc3[3];
      const float ig = fast_sig(Gi), fg = fast_sig(Gf);
      const float gg = fast_tanh(Gg), og = fast_sig(Go);
      c_reg = fg * c_reg + ig * gg;
      const float h = og * fast_tanh(c_reg);
      const int jl = wt * 4 + quad;          // local unit 0..15
      ((short*)htile)[((jl >> 3) * 16 + col16) * 8 + (jl & 7)] = (short)f2bf(h);
    }
    if (tt >= 1 && grp == 1 && v < 8) {      // ysA(t-1), o-tile v
      f32x4 yacc = {0.f, 0.f, 0.f, 0.f};
      #pragma unroll
      for (int i = 0; i < 8; i++) {
        const int kt = wt * 8 + i;
        const short8 bf = *(const short8*)(woutf + ((size_t)(v * 32 + kt) * 64 + lane) * 16);
        const short8 af = a_lds[kt * 64 + lane];
        yacc = __builtin_amdgcn_mfma_f32_16x16x32_bf16(af, bf, yacc, 0, 0, 0);
      }
      *(f32x4*)&ysred[(wt * 16 + (lane & 15)) * 20 + (lane >> 4) * 4] = yacc;
    }
    __syncthreads();  // s3
    // ====== P3: publish A (wave0) | ysA reduce (tid>=256) | z0B | spin B =====
    if (tt < Tn && w == 0) {
      const u64 hv = htile[lane];
      u64* dstp = (u64*)(hbuf + (size_t)((tt & 1) * 8 + gA) * 32768 +
                         (size_t)v * 512 + (size_t)lane * 8);
      __hip_atomic_store(dstp, hv, __ATOMIC_RELAXED, __HIP_MEMORY_SCOPE_SYSTEM);
      asm volatile("s_waitcnt vmcnt(0)" ::: "memory");
      if (tid == 0)
        __hip_atomic_fetch_add(&cnt[gA * 1024 + tt], 1, __ATOMIC_RELAXED,
                               __HIP_MEMORY_SCOPE_SYSTEM);
    }
    if (tt >= 1 && v < 8 && tid >= 256) {    // ysA reduce + out store (group A)
      const int idx = tid - 256;
      const int o = idx & 15, b = idx >> 4;
      float s = 0.f;
      #pragma unroll
      for (int q = 0; q < 4; q++) s += ysred[(q * 16 + o) * 20 + b];
      s += bo_lds[o];
      const float val = ((tt - 1) < seq_lds[b]) ? s : 0.0f;
      out[((size_t)(p * 32 + b) * Tn + (tt - 1)) * 128 + v * 16 + o] = val;
    }
    if (tt == 0 && tid >= 256) {             // stage z0B (ys inactive at t=0)
      const int kz = (tid - 256) >> 6, ln = tid & 63;
      a_lds[(36 + kz) * 64 + ln] =
          *(const short8*)(ws + WS_Z0 + ((size_t)(gB * 4 + kz) * 64 + ln) * 16);
    }
    if (tt >= 1 && tid == 64) {              // spin B(t-1) (wave1 idle here)
      while (__hip_atomic_load(&cnt[gB * 1024 + (tt - 1)], __ATOMIC_RELAXED,
                               __HIP_MEMORY_SCOPE_SYSTEM) < 64) {}
    }
    __syncthreads();  // s4
    // ================ P4: stage hB(t-1) + xB(t) ================
    {
      const u64* src = (const u64*)(hbuf + (size_t)((((tt + 1) & 1) * 8) + gB) * 32768);
      u64 tmp[8];
      #pragma unroll
      for (int s = 0; s < 8; s++)
        tmp[s] = __hip_atomic_load(&src[s * 512 + tid], __ATOMIC_RELAXED,
                                   __HIP_MEMORY_SCOPE_SYSTEM);
      u64* dst = (u64*)a_lds;
      #pragma unroll
      for (int s = 0; s < 8; s++) dst[s * 512 + tid] = tmp[s];
    }
    if (tt < Tn && tid < 256) {              // stage xB(t)
      const int kt4 = tid >> 6, ln = tid & 63;
      const int b = ln & 15, qd = ln >> 4;
      const int i0 = kt4 * 32 + qd * 8;
      const float* xp = x + ((size_t)(p * 32 + 16 + b) * Tn + tt) * In + i0;
      const float mk = (tt < seq_lds[16 + b]) ? 1.0f : 0.0f;
      const f32x4 x0 = *(const f32x4*)xp;
      const f32x4 x1 = *(const f32x4*)(xp + 4);
      short8 pk;
      pk[0] = (short)f2bf(x0[0] * mk); pk[1] = (short)f2bf(x0[1] * mk);
      pk[2] = (short)f2bf(x0[2] * mk); pk[3] = (short)f2bf(x0[3] * mk);
      pk[4] = (short)f2bf(x1[0] * mk); pk[5] = (short)f2bf(x1[1] * mk);
      pk[6] = (short)f2bf(x1[2] * mk); pk[7] = (short)f2bf(x1[3] * mk);
      a_lds[(32 + kt4) * 64 + ln] = pk;
    }
    __syncthreads();  // s5
    // ====== P5: gates B (waves 4-7) || ysB(t-1) (v in 8..16, waves 0-3) ======
    if (tt < Tn && grp == 1) {
      f32x4 acc0 = {bias_g[0], bias_g[1], bias_g[2], bias_g[3]};
      f32x4 acc1 = {0.f, 0.f, 0.f, 0.f};
      f32x4 acc2 = {0.f, 0.f, 0.f, 0.f};
      f32x4 acc3 = {0.f, 0.f, 0.f, 0.f};
      #pragma unroll
      for (int kk = 0; kk < 9; kk++) {
        const short8 a0 = a_lds[(kk * 4 + 0) * 64 + lane];
        const short8 a1 = a_lds[(kk * 4 + 1) * 64 + lane];
        const short8 a2 = a_lds[(kk * 4 + 2) * 64 + lane];
        const short8 a3 = a_lds[(kk * 4 + 3) * 64 + lane];
        acc0 = __builtin_amdgcn_mfma_f32_16x16x32_bf16(bfr[kk * 4 + 0], a0, acc0, 0, 0, 0);
        acc1 = __builtin_amdgcn_mfma_f32_16x16x32_bf16(bfr[kk * 4 + 1], a1, acc1, 0, 0, 0);
        acc2 = __builtin_amdgcn_mfma_f32_16x16x32_bf16(bfr[kk * 4 + 2], a2, acc2, 0, 0, 0);
        acc3 = __builtin_amdgcn_mfma_f32_16x16x32_bf16(bfr[kk * 4 + 3], a3, acc3, 0, 0, 0);
      }
      if (tt == 0) {
        const short8 z0 = a_lds[36 * 64 + lane];
        const short8 z1 = a_lds[37 * 64 + lane];
        const short8 z2 = a_lds[38 * 64 + lane];
        const short8 z3 = a_lds[39 * 64 + lane];
        acc0 = __builtin_amdgcn_mfma_f32_16x16x32_bf16(bfr[36], z0, acc0, 0, 0, 0);
        acc1 = __builtin_amdgcn_mfma_f32_16x16x32_bf16(bfr[37], z1, acc1, 0, 0, 0);
        acc2 = __builtin_amdgcn_mfma_f32_16x16x32_bf16(bfr[38], z2, acc2, 0, 0, 0);
        acc3 = __builtin_amdgcn_mfma_f32_16x16x32_bf16(bfr[39], z3, acc3, 0, 0, 0);
      }
      const float Gi = acc0[0] + acc1[0] + acc2[0] + acc3[0];
      const float Gf = acc0[1] + acc1[1] + acc2[1] + acc3[1];
      const float Gg = acc0[2] + acc1[2] + acc2[2] + acc3[2];
      const float Go = acc0[3] + acc1[3] + acc2[3] + acc3[3];
      const float ig = fast_sig(Gi), fg = fast_sig(Gf);
      const float gg = fast_tanh(Gg), og = fast_sig(Go);
      c_reg = fg * c_reg + ig * gg;
      const float h = og * fast_tanh(c_reg);
      const int jl = wt * 4 + quad;
      ((short*)htile)[((jl >> 3) * 16 + col16) * 8 + (jl & 7)] = (short)f2bf(h);
    }
    if (tt >= 1 && grp == 0 && v >= 8 && v < 16) {   // ysB(t-1), o-tile v-8
      f32x4 yacc = {0.f, 0.f, 0.f, 0.f};
      #pragma unroll
      for (int i = 0; i < 8; i++) {
        const int kt = wt * 8 + i;
        const short8 bf =
            *(const short8*)(woutf + ((size_t)((v - 8) * 32 + kt) * 64 + lane) * 16);
        const short8 af = a_lds[kt * 64 + lane];
        yacc = __builtin_amdgcn_mfma_f32_16x16x32_bf16(af, bf, yacc, 0, 0, 0);
      }
      *(f32x4*)&ysred[(wt * 16 + (lane & 15)) * 20 + (lane >> 4) * 4] = yacc;
    }
    __syncthreads();  // s6
    // ================ P6: publish B (wave4) | ysB reduce (tid<256) ===========
    if (tt < Tn && w == 4) {
      const u64 hv = htile[lane];
      u64* dstp = (u64*)(hbuf + (size_t)((tt & 1) * 8 + gB) * 32768 +
                         (size_t)v * 512 + (size_t)lane * 8);
      __hip_atomic_store(dstp, hv, __ATOMIC_RELAXED, __HIP_MEMORY_SCOPE_SYSTEM);
      asm volatile("s_waitcnt vmcnt(0)" ::: "memory");
      if (tid == 256)
        __hip_atomic_fetch_add(&cnt[gB * 1024 + tt], 1, __ATOMIC_RELAXED,
                               __HIP_MEMORY_SCOPE_SYSTEM);
    }
    if (tt >= 1 && v >= 8 && v < 16 && tid < 256) {  // ysB reduce + out (group B)
      const int o = tid & 15, b = tid >> 4;
      float s = 0.f;
      #pragma unroll
      for (int q = 0; q < 4; q++) s += ysred[(q * 16 + o) * 20 + b];
      s += bo_lds[o];
      const float val = ((tt - 1) < seq_lds[16 + b]) ? s : 0.0f;
      out[((size_t)(p * 32 + 16 + b) * Tn + (tt - 1)) * 128 + (v - 8) * 16 + o] = val;
    }
    __syncthreads();  // s7 (trailing; drains out stores where they're cheap)
  }
}

extern "C" void kernel_launch(void* const* d_in, const int* in_sizes, int n_in,
                              void* d_out, int out_size, void* d_ws, size_t ws_size,
                              hipStream_t stream) {
  (void)in_sizes; (void)n_in; (void)out_size; (void)ws_size;
  const float* x    = (const float*)d_in[0];
  const int*   seq  = (const int*)d_in[1];
  const float* hn   = (const float*)d_in[2];
  const float* cn   = (const float*)d_in[3];
  const float* outt = (const float*)d_in[4];
  const float* Wih  = (const float*)d_in[5];
  const float* Whh  = (const float*)d_in[6];
  const float* bih  = (const float*)d_in[7];
  const float* bhh  = (const float*)d_in[8];
  const float* Wout = (const float*)d_in[9];
  const float* bout = (const float*)d_in[10];
  float* out = (float*)d_out;
  char* ws = (char*)d_ws;

  hipLaunchKernelGGL(k_wfrag, dim3(32, 8, 40), dim3(64), 0, stream, Wih, Whh, Wout, ws);
  hipLaunchKernelGGL(k_misc, dim3(616), dim3(64), 0, stream, Wout, hn, outt, bout,
                     bih, bhh, Wih, out, ws);
  void* args[] = {(void*)&x, (void*)&seq, (void*)&cn, (void*)&bout, (void*)&out, (void*)&ws};
  hipLaunchCooperativeKernel((const void*)k_main, dim3(256), dim3(512), args, 0, stream);
}